// Round 2
// baseline (3996.160 us; speedup 1.0000x reference)
//
#include <hip/hip_runtime.h>

#define DD 48
#define HF 256
#define WF 320
#define HH 128
#define WH 160
#define NPF (HF * WF)     // 81920
#define NPH (HH * WH)     // 20480
#define S1SZ (8 * NPF)    // one s1-class slice (floats)
#define S2SZ (16 * NPH)   // one s2-class slice (floats)

__device__ __forceinline__ float sigf(float x) { return 1.0f / (1.0f + __expf(-x)); }
__device__ __forceinline__ float tanh_(float x) {
    float e = __expf(2.0f * x);
    return 1.0f - 2.0f / (e + 1.0f);
}

// ---- 2-px conv core -------------------------------------------------------
template<int Ht, int Wt>
__device__ __forceinline__ void taps2(int y, int x0, int* off, float* msk) {
    int cx[4]; float cm[4];
    cx[0] = max(x0 - 1, 0);      cm[0] = (x0 > 0) ? 1.0f : 0.0f;
    cx[1] = x0;                  cm[1] = 1.0f;
    cx[2] = x0 + 1;              cm[2] = 1.0f;                      // x0+1 <= Wt-1 always
    cx[3] = min(x0 + 2, Wt - 1); cm[3] = (x0 + 2 < Wt) ? 1.0f : 0.0f;
#pragma unroll
    for (int r = 0; r < 3; ++r) {
        int yy = y - 1 + r;
        float rm = ((unsigned)yy < (unsigned)Ht) ? 1.0f : 0.0f;
        int rb = min(max(yy, 0), Ht - 1) * Wt;
#pragma unroll
        for (int k = 0; k < 4; ++k) {
            off[r * 4 + k] = rb + cx[k];
            msk[r * 4 + k] = rm * cm[k];
        }
    }
}

template<int CI, int COUT>
__device__ __forceinline__ void acc2px(
    const float* __restrict__ in, int cs,
    const float* __restrict__ w, int wcs,
    const int* off, const float* msk,
    float* a0, float* a1)
{
#pragma unroll 2
    for (int ci = 0; ci < CI; ++ci) {
        const float* p = in + ci * cs;
        float v[12];
#pragma unroll
        for (int k = 0; k < 12; ++k) v[k] = p[off[k]] * msk[k];
        const float* wp = w + ci * 9;
#pragma unroll
        for (int j = 0; j < COUT; ++j) {
            const float* wc = wp + j * wcs;
#pragma unroll
            for (int r = 0; r < 3; ++r) {
                a0[j] = fmaf(v[r * 4 + 0], wc[r * 3 + 0], a0[j]);
                a0[j] = fmaf(v[r * 4 + 1], wc[r * 3 + 1], a0[j]);
                a0[j] = fmaf(v[r * 4 + 2], wc[r * 3 + 2], a0[j]);
                a1[j] = fmaf(v[r * 4 + 1], wc[r * 3 + 0], a1[j]);
                a1[j] = fmaf(v[r * 4 + 2], wc[r * 3 + 1], a1[j]);
                a1[j] = fmaf(v[r * 4 + 3], wc[r * 3 + 2], a1[j]);
            }
        }
    }
}

// ---- conv1 role: vertical 4-px strip per thread, lane-dense loads ---------
__device__ __forceinline__ void conv1_role(
    const float* __restrict__ x, const float* __restrict__ w,
    const float* __restrict__ b, float* __restrict__ o_slice,
    int dsl, int pb)
{
    const int t = pb * 256 + threadIdx.x;   // [0, 20480) per slice
    const int xc = t % WF;
    const int yb = (t / WF) * 4;
    const float* __restrict__ xin = x + (long)dsl * NPF;
    const int cxm = max(xc - 1, 0), cxp = min(xc + 1, WF - 1);
    const float cmm = (xc > 0) ? 1.0f : 0.0f;
    const float cmp = (xc < WF - 1) ? 1.0f : 0.0f;
    int off[18]; float msk[18];
#pragma unroll
    for (int r = 0; r < 6; ++r) {
        const int yy = yb - 1 + r;
        const float rm = ((unsigned)yy < (unsigned)HF) ? 1.0f : 0.0f;
        const int rb = min(max(yy, 0), HF - 1) * WF;
        off[r * 3 + 0] = rb + cxm; msk[r * 3 + 0] = rm * cmm;
        off[r * 3 + 1] = rb + xc;  msk[r * 3 + 1] = rm;
        off[r * 3 + 2] = rb + cxp; msk[r * 3 + 2] = rm * cmp;
    }
    float acc[4][8];
#pragma unroll
    for (int j = 0; j < 8; ++j) {
        const float bj = b[j];
#pragma unroll
        for (int q = 0; q < 4; ++q) acc[q][j] = bj;
    }
#pragma unroll 2
    for (int ci = 0; ci < 32; ++ci) {
        const float* p = xin + (long)ci * (DD * NPF);
        float v[18];
#pragma unroll
        for (int k = 0; k < 18; ++k) v[k] = p[off[k]] * msk[k];
        const float* wp = w + ci * 9;                 // w (8,32,3,3): cout stride 288
#pragma unroll
        for (int j = 0; j < 8; ++j) {
            const float* wc = wp + j * (32 * 9);
#pragma unroll
            for (int q = 0; q < 4; ++q) {
#pragma unroll
                for (int r = 0; r < 3; ++r) {
                    acc[q][j] = fmaf(v[(q + r) * 3 + 0], wc[r * 3 + 0], acc[q][j]);
                    acc[q][j] = fmaf(v[(q + r) * 3 + 1], wc[r * 3 + 1], acc[q][j]);
                    acc[q][j] = fmaf(v[(q + r) * 3 + 2], wc[r * 3 + 2], acc[q][j]);
                }
            }
        }
    }
    float* o = o_slice + yb * WF + xc;
#pragma unroll
    for (int j = 0; j < 8; ++j)
#pragma unroll
        for (int q = 0; q < 4; ++q)
            o[j * NPF + q * WF] = fmaxf(acc[q][j], 0.0f);
}

__global__ __launch_bounds__(256) void k_conv1(
    const float* __restrict__ x, const float* __restrict__ w,
    const float* __restrict__ b, float* __restrict__ out,
    int d0, int ostride)
{
    conv1_role(x, w, b, out + (long)blockIdx.z * ostride, d0 + blockIdx.z, blockIdx.x);
}

// ---- gates role -----------------------------------------------------------
template<int C, int Ht, int Wt, int CO>
__device__ __forceinline__ void gates_role(
    const float* __restrict__ a, const float* __restrict__ s,
    const float* __restrict__ w, const float* __restrict__ b,
    float* __restrict__ rh, float* __restrict__ u, int pb, int cog)
{
    constexpr int NP = Ht * Wt;
    const int pix0 = (pb * 256 + threadIdx.x) * 2;
    const int y = pix0 / Wt, x0 = pix0 - y * Wt;
    const int co0 = cog * CO;
    int off[12]; float msk[12];
    taps2<Ht, Wt>(y, x0, off, msk);
    float a0[CO], a1[CO];
#pragma unroll
    for (int j = 0; j < CO; ++j) { a0[j] = b[co0 + j]; a1[j] = b[co0 + j]; }
    acc2px<C, CO>(a, NP, w + co0 * (2 * C * 9), 2 * C * 9, off, msk, a0, a1);
    acc2px<C, CO>(s, NP, w + co0 * (2 * C * 9) + C * 9, 2 * C * 9, off, msk, a0, a1);
    if (co0 < C) {
#pragma unroll
        for (int j = 0; j < CO; ++j) {
            int o = (co0 + j) * NP + pix0;
            rh[o]     = sigf(a0[j]) * s[o];
            rh[o + 1] = sigf(a1[j]) * s[o + 1];
        }
    } else {
#pragma unroll
        for (int j = 0; j < CO; ++j) {
            int o = (co0 - C + j) * NP + pix0;
            u[o]     = sigf(a0[j]);
            u[o + 1] = sigf(a1[j]);
        }
    }
}

// ---- cand role ------------------------------------------------------------
template<int C, int Ht, int Wt, int CO>
__device__ __forceinline__ void cand_role(
    const float* __restrict__ a, const float* __restrict__ rh,
    const float* __restrict__ w, const float* __restrict__ b,
    const float* __restrict__ u, const float* __restrict__ sprev,
    float* __restrict__ sout, int pb, int cog)
{
    constexpr int NP = Ht * Wt;
    const int pix0 = (pb * 256 + threadIdx.x) * 2;
    const int y = pix0 / Wt, x0 = pix0 - y * Wt;
    const int co0 = cog * CO;
    int off[12]; float msk[12];
    taps2<Ht, Wt>(y, x0, off, msk);
    float a0[CO], a1[CO];
#pragma unroll
    for (int j = 0; j < CO; ++j) { a0[j] = b[co0 + j]; a1[j] = b[co0 + j]; }
    acc2px<C, CO>(a, NP, w + co0 * (2 * C * 9), 2 * C * 9, off, msk, a0, a1);
    acc2px<C, CO>(rh, NP, w + co0 * (2 * C * 9) + C * 9, 2 * C * 9, off, msk, a0, a1);
#pragma unroll
    for (int j = 0; j < CO; ++j) {
        int o = (co0 + j) * NP + pix0;
        float c0 = tanh_(a0[j]);
        float c1 = tanh_(a1[j]);
        sout[o]     = fmaf(u[o],     sprev[o]     - c0, c0);
        sout[o + 1] = fmaf(u[o + 1], sprev[o + 1] - c1, c1);
    }
}

// ---- conv2 role: stride-2 3x3 pad1, (8,HF,WF) -> relu -> (16,HH,WH) -------
__device__ __forceinline__ void conv2_role(
    const float* __restrict__ s1, const float* __restrict__ w,
    const float* __restrict__ b, float* __restrict__ c2, int pb, int cog)
{
    const int pix0 = (pb * 256 + threadIdx.x) * 2;  // output px in NPH
    const int y = pix0 / WH, x0 = pix0 - y * WH;    // x0 even, <= WH-2
    const int co0 = cog * 8;
    int off[15]; float msk[15];
    {
        int cx[5]; float cm[5];
        cx[0] = max(2 * x0 - 1, 0); cm[0] = (x0 > 0) ? 1.0f : 0.0f;
#pragma unroll
        for (int i = 1; i < 5; ++i) { cx[i] = 2 * x0 - 1 + i; cm[i] = 1.0f; }
#pragma unroll
        for (int r = 0; r < 3; ++r) {
            int yy = 2 * y - 1 + r;
            float rm = ((unsigned)yy < (unsigned)HF) ? 1.0f : 0.0f;
            int rb = min(max(yy, 0), HF - 1) * WF;
#pragma unroll
            for (int i = 0; i < 5; ++i) { off[r * 5 + i] = rb + cx[i]; msk[r * 5 + i] = rm * cm[i]; }
        }
    }
    float a0[8], a1[8];
#pragma unroll
    for (int j = 0; j < 8; ++j) { a0[j] = b[co0 + j]; a1[j] = b[co0 + j]; }
#pragma unroll 2
    for (int ci = 0; ci < 8; ++ci) {
        const float* p = s1 + ci * NPF;
        float v[15];
#pragma unroll
        for (int k = 0; k < 15; ++k) v[k] = p[off[k]] * msk[k];
        const float* wp = w + co0 * 72 + ci * 9;   // w (16,8,3,3), cout stride 72
#pragma unroll
        for (int j = 0; j < 8; ++j) {
            const float* wc = wp + j * 72;
#pragma unroll
            for (int r = 0; r < 3; ++r) {
                a0[j] = fmaf(v[r * 5 + 0], wc[r * 3 + 0], a0[j]);
                a0[j] = fmaf(v[r * 5 + 1], wc[r * 3 + 1], a0[j]);
                a0[j] = fmaf(v[r * 5 + 2], wc[r * 3 + 2], a0[j]);
                a1[j] = fmaf(v[r * 5 + 2], wc[r * 3 + 0], a1[j]);
                a1[j] = fmaf(v[r * 5 + 3], wc[r * 3 + 1], a1[j]);
                a1[j] = fmaf(v[r * 5 + 4], wc[r * 3 + 2], a1[j]);
            }
        }
    }
#pragma unroll
    for (int j = 0; j < 8; ++j) {
        c2[(co0 + j) * NPH + pix0]     = fmaxf(a0[j], 0.0f);
        c2[(co0 + j) * NPH + pix0 + 1] = fmaxf(a1[j], 0.0f);
    }
}

// ---- up1 role: ConvTranspose2d(16->8,k3,s2,p1,op1) + s1 skip + relu -------
__device__ __forceinline__ void up1_role(
    const float* __restrict__ s2, const float* __restrict__ w,
    const float* __restrict__ b, const float* __restrict__ s1,
    float* __restrict__ ubuf, int pb)
{
    const int q = pb * 256 + threadIdx.x;  // < NPH
    const int r = q / WH, c = q - r * WH;
    const int dc = (c + 1 < WH) ? 1 : 0;
    const int dr = (r + 1 < HH) ? WH : 0;
    const float mc = (c + 1 < WH) ? 1.0f : 0.0f;
    const float mr = (r + 1 < HH) ? 1.0f : 0.0f;
    const float mrc = mc * mr;
    float a00[8], a01[8], a10[8], a11[8];
#pragma unroll
    for (int j = 0; j < 8; ++j) { a00[j] = b[j]; a01[j] = b[j]; a10[j] = b[j]; a11[j] = b[j]; }
#pragma unroll 2
    for (int ci = 0; ci < 16; ++ci) {
        const float* p = s2 + ci * NPH + r * WH + c;
        float v00 = p[0];
        float v01 = p[dc] * mc;
        float v10 = p[dr] * mr;
        float v11 = p[dr + dc] * mrc;
        const float* wp = w + ci * 8 * 9;
#pragma unroll
        for (int j = 0; j < 8; ++j) {
            const float* wc = wp + j * 9;
            a00[j] = fmaf(v00, wc[4], a00[j]);
            a01[j] = fmaf(v01, wc[3], fmaf(v00, wc[5], a01[j]));
            a10[j] = fmaf(v10, wc[1], fmaf(v00, wc[7], a10[j]));
            a11[j] = fmaf(v11, wc[0], fmaf(v10, wc[2], fmaf(v01, wc[6], fmaf(v00, wc[8], a11[j]))));
        }
    }
    const int o0 = (2 * r) * WF + 2 * c;
#pragma unroll
    for (int j = 0; j < 8; ++j) {
        int o = j * NPF + o0;
        ubuf[o]          = fmaxf(a00[j] + s1[o], 0.0f);
        ubuf[o + 1]      = fmaxf(a01[j] + s1[o + 1], 0.0f);
        ubuf[o + WF]     = fmaxf(a10[j] + s1[o + WF], 0.0f);
        ubuf[o + WF + 1] = fmaxf(a11[j] + s1[o + WF + 1], 0.0f);
    }
}

// ---- up2 role: ConvTranspose2d(8->1,k3,s2,p1,op1) -> out slice (512,640) --
__device__ __forceinline__ void up2_role(
    const float* __restrict__ u, const float* __restrict__ w,
    const float* __restrict__ b, float* __restrict__ oslice, int pb)
{
    const int q = pb * 256 + threadIdx.x;  // < NPF
    const int r = q / WF, c = q - r * WF;
    const int dc = (c + 1 < WF) ? 1 : 0;
    const int dr = (r + 1 < HF) ? WF : 0;
    const float mc = (c + 1 < WF) ? 1.0f : 0.0f;
    const float mr = (r + 1 < HF) ? 1.0f : 0.0f;
    const float mrc = mc * mr;
    const float b0 = b[0];
    float a00 = b0, a01 = b0, a10 = b0, a11 = b0;
#pragma unroll 2
    for (int ci = 0; ci < 8; ++ci) {
        const float* p = u + ci * NPF + r * WF + c;
        float v00 = p[0];
        float v01 = p[dc] * mc;
        float v10 = p[dr] * mr;
        float v11 = p[dr + dc] * mrc;
        const float* wc = w + ci * 9;
        a00 = fmaf(v00, wc[4], a00);
        a01 = fmaf(v01, wc[3], fmaf(v00, wc[5], a01));
        a10 = fmaf(v10, wc[1], fmaf(v00, wc[7], a10));
        a11 = fmaf(v11, wc[0], fmaf(v10, wc[2], fmaf(v01, wc[6], fmaf(v00, wc[8], a11))));
    }
    float* o = oslice + (2 * r) * 640 + 2 * c;
    o[0] = a00; o[1] = a01; o[640] = a10; o[641] = a11;
}

// ---- fused skewed-chain steps ---------------------------------------------
// A(d): gates1(d) [0,320) | gates2(d-2) [320,640) | conv1(d+2) [640,720) |
//       up1(d-3) [720,800)
__global__ __launch_bounds__(256) void k_stepA(
    const float* __restrict__ x, const float* __restrict__ w1,
    const float* __restrict__ b1, float* __restrict__ c1_all,
    const float* __restrict__ s1_all,
    const float* __restrict__ wg1, const float* __restrict__ bg1,
    float* __restrict__ rh1, float* __restrict__ ug1,
    const float* __restrict__ c2_all, const float* __restrict__ s2_all,
    const float* __restrict__ wg2, const float* __restrict__ bg2,
    float* __restrict__ rh2, float* __restrict__ ug2,
    const float* __restrict__ wu1, const float* __restrict__ bu1,
    float* __restrict__ ubuf,
    int d1, int d2, int dcv1, int du1)
{
    const int bid = blockIdx.x;
    if (bid < 320) {
        if (d1 < 0) return;
        gates_role<8, HF, WF, 8>(c1_all + (long)d1 * S1SZ, s1_all + (long)d1 * S1SZ,
                                 wg1, bg1, rh1, ug1, bid % 160, bid / 160);
    } else if (bid < 640) {
        if (d2 < 0) return;
        const int bb = bid - 320;
        gates_role<16, HH, WH, 4>(c2_all + (long)d2 * S2SZ, s2_all + (long)d2 * S2SZ,
                                  wg2, bg2, rh2, ug2, bb % 40, bb / 40);
    } else if (bid < 720) {
        if (dcv1 < 0) return;
        conv1_role(x, w1, b1, c1_all + (long)dcv1 * S1SZ, dcv1, bid - 640);
    } else {
        if (du1 < 0) return;
        up1_role(s2_all + (long)(du1 + 1) * S2SZ, wu1, bu1,
                 s1_all + (long)(du1 + 1) * S1SZ, ubuf, bid - 720);
    }
}

// B(d): cand1(d) [0,160) | conv2(d-1) [160,240) | cand2(d-2) [240,400) |
//       up2(d-3) [400,720)
__global__ __launch_bounds__(256) void k_stepB(
    const float* __restrict__ c1_all, float* __restrict__ s1_all,
    const float* __restrict__ wc1, const float* __restrict__ bc1,
    const float* __restrict__ rh1, const float* __restrict__ ug1,
    const float* __restrict__ w2, const float* __restrict__ b2,
    float* __restrict__ c2_all, float* __restrict__ s2_all,
    const float* __restrict__ wc2, const float* __restrict__ bc2,
    const float* __restrict__ rh2, const float* __restrict__ ug2,
    const float* __restrict__ wu2, const float* __restrict__ bu2,
    const float* __restrict__ ubuf, float* __restrict__ out,
    int d1, int dc, int d2, int du2)
{
    const int bid = blockIdx.x;
    if (bid < 160) {
        if (d1 < 0) return;
        cand_role<8, HF, WF, 8>(c1_all + (long)d1 * S1SZ, rh1, wc1, bc1, ug1,
                                s1_all + (long)d1 * S1SZ, s1_all + (long)(d1 + 1) * S1SZ,
                                bid, 0);
    } else if (bid < 240) {
        if (dc < 0) return;
        const int bb = bid - 160;
        conv2_role(s1_all + (long)(dc + 1) * S1SZ, w2, b2,
                   c2_all + (long)dc * S2SZ, bb % 40, bb / 40);
    } else if (bid < 400) {
        if (d2 < 0) return;
        const int bb = bid - 240;
        cand_role<16, HH, WH, 4>(c2_all + (long)d2 * S2SZ, rh2, wc2, bc2, ug2,
                                 s2_all + (long)d2 * S2SZ, s2_all + (long)(d2 + 1) * S2SZ,
                                 bb % 40, bb / 40);
    } else {
        if (du2 < 0) return;
        up2_role(ubuf, wu2, bu2, out + (long)du2 * (512 * 640), bid - 400);
    }
}

// ---- standalone wrappers (fallback path) ----------------------------------
template<int C, int Ht, int Wt, int CO>
__global__ __launch_bounds__(256) void k_gates(
    const float* __restrict__ a, const float* __restrict__ s,
    const float* __restrict__ w, const float* __restrict__ b,
    float* __restrict__ rh, float* __restrict__ u)
{ gates_role<C, Ht, Wt, CO>(a, s, w, b, rh, u, blockIdx.x, blockIdx.y); }

template<int C, int Ht, int Wt, int CO>
__global__ __launch_bounds__(256) void k_cand(
    const float* __restrict__ a, const float* __restrict__ rh,
    const float* __restrict__ w, const float* __restrict__ b,
    const float* __restrict__ u, const float* __restrict__ sprev,
    float* __restrict__ sout)
{ cand_role<C, Ht, Wt, CO>(a, rh, w, b, u, sprev, sout, blockIdx.x, blockIdx.y); }

__global__ __launch_bounds__(256) void k_conv2w(
    const float* __restrict__ s1, const float* __restrict__ w,
    const float* __restrict__ b, float* __restrict__ c2)
{ conv2_role(s1, w, b, c2, blockIdx.x, blockIdx.y); }

__global__ __launch_bounds__(256) void k_up1(
    const float* __restrict__ s2b, int zs2,
    const float* __restrict__ w, const float* __restrict__ b,
    const float* __restrict__ s1b, int zs1,
    float* __restrict__ ub, int zu)
{
    up1_role(s2b + (long)blockIdx.z * zs2, w, b,
             s1b + (long)blockIdx.z * zs1, ub + (long)blockIdx.z * zu, blockIdx.x);
}

__global__ __launch_bounds__(256) void k_up2(
    const float* __restrict__ ub, int zu,
    const float* __restrict__ w, const float* __restrict__ b,
    float* __restrict__ out, int d0)
{
    up2_role(ub + (long)blockIdx.z * zu, w, b,
             out + (long)(d0 + blockIdx.z) * (512 * 640), blockIdx.x);
}

extern "C" void kernel_launch(void* const* d_in, const int* in_sizes, int n_in,
                              void* d_out, int out_size, void* d_ws, size_t ws_size,
                              hipStream_t stream)
{
    const float* x   = (const float*)d_in[0];
    const float* w1  = (const float*)d_in[1];
    const float* b1  = (const float*)d_in[2];
    const float* wg1 = (const float*)d_in[3];
    const float* bg1 = (const float*)d_in[4];
    const float* wc1 = (const float*)d_in[5];
    const float* bc1 = (const float*)d_in[6];
    const float* w2  = (const float*)d_in[7];
    const float* b2  = (const float*)d_in[8];
    const float* wg2 = (const float*)d_in[9];
    const float* bg2 = (const float*)d_in[10];
    const float* wc2 = (const float*)d_in[11];
    const float* bc2 = (const float*)d_in[12];
    const float* wu1 = (const float*)d_in[13];
    const float* bu1 = (const float*)d_in[14];
    const float* wu2 = (const float*)d_in[15];
    const float* bu2 = (const float*)d_in[16];
    float* out = (float*)d_out;
    float* ws = (float*)d_ws;

    // ---- full-history schedule: skewed fused chains + folded bulk work ----
    {
        float* p = ws;
        float* s1_all = p; p += 49L * S1SZ;   // slice 0 = zeros
        float* s2_all = p; p += 49L * S2SZ;
        float* c2_all = p; p += 48L * S2SZ;
        float* rh1 = p; p += S1SZ;
        float* ug1 = p; p += S1SZ;
        float* rh2 = p; p += S2SZ;
        float* ug2 = p; p += S2SZ;
        float* ubuf = p; p += S1SZ;           // single up1->up2 slice (A(d)->B(d))
        float* c1_all = p; p += 48L * S1SZ;
        const size_t need = (size_t)(p - ws) * sizeof(float);
        if (ws_size >= need) {
            hipMemsetAsync(s1_all, 0, (size_t)S1SZ * sizeof(float), stream);
            hipMemsetAsync(s2_all, 0, (size_t)S2SZ * sizeof(float), stream);

            // Prologue: conv1 for slices 0,1 (chain folds in slice d+2).
            k_conv1<<<dim3(80, 1, 2), 256, 0, stream>>>(x, w1, b1, c1_all, 0, S1SZ);
            // Skew (all producers >= 1 dispatch ahead of consumers):
            //   A(d): gates1(d) | gates2(d-2) | conv1(d+2) | up1(d-3)
            //   B(d): cand1(d) | conv2(d-1) | cand2(d-2) | up2(d-3)
            // up1(k) reads s2_all[k+1] (cand2(k) in B(k+2)) and s1_all[k+1]
            // (cand1(k) in B(k)); ubuf written A(d), read B(d), rewritten
            // A(d+1) -- stream-serial => safe.
            for (int d = 0; d <= 50; ++d) {
                const int g1  = (d < 48) ? d : -1;
                const int g2  = (d >= 2 && d <= 49) ? d - 2 : -1;
                const int cv1 = (d + 2 < 48) ? d + 2 : -1;
                const int u1  = (d >= 3) ? d - 3 : -1;          // <= 47 since d <= 50
                const int cv  = (d >= 1 && d <= 48) ? d - 1 : -1;
                k_stepA<<<dim3(800), 256, 0, stream>>>(
                    x, w1, b1, c1_all, s1_all, wg1, bg1, rh1, ug1,
                    c2_all, s2_all, wg2, bg2, rh2, ug2,
                    wu1, bu1, ubuf, g1, g2, cv1, u1);
                k_stepB<<<dim3(720), 256, 0, stream>>>(
                    c1_all, s1_all, wc1, bc1, rh1, ug1,
                    w2, b2, c2_all, s2_all, wc2, bc2, rh2, ug2,
                    wu2, bu2, ubuf, out, g1, cv, g2, u1);
            }
            return;
        }
    }

    // ---- fallback: small-workspace interleaved schedule ----
    {
        float* p = ws;
        float* s1 = p; p += S1SZ;
        float* s2 = p; p += S2SZ;
        float* rh1 = p; p += S1SZ;
        float* ug1 = p; p += S1SZ;
        float* c2 = p; p += S2SZ;
        float* rh2 = p; p += S2SZ;
        float* ug2 = p; p += S2SZ;
        float* c1 = p; p += S1SZ;
        float* u = p; p += S1SZ;
        hipMemsetAsync(s1, 0, (size_t)S1SZ * sizeof(float), stream);
        hipMemsetAsync(s2, 0, (size_t)S2SZ * sizeof(float), stream);
        for (int d = 0; d < 48; ++d) {
            k_conv1<<<dim3(80, 1, 1), 256, 0, stream>>>(x, w1, b1, c1, d, 0);
            k_gates<8, HF, WF, 8><<<dim3(160, 2), 256, 0, stream>>>(c1, s1, wg1, bg1, rh1, ug1);
            k_cand <8, HF, WF, 8><<<dim3(160, 1), 256, 0, stream>>>(c1, rh1, wc1, bc1, ug1, s1, s1);
            k_conv2w<<<dim3(40, 2), 256, 0, stream>>>(s1, w2, b2, c2);
            k_gates<16, HH, WH, 8><<<dim3(40, 4), 256, 0, stream>>>(c2, s2, wg2, bg2, rh2, ug2);
            k_cand <16, HH, WH, 8><<<dim3(40, 2), 256, 0, stream>>>(c2, rh2, wc2, bc2, ug2, s2, s2);
            k_up1<<<dim3(80, 1, 1), 256, 0, stream>>>(s2, 0, wu1, bu1, s1, 0, u, 0);
            k_up2<<<dim3(320, 1, 1), 256, 0, stream>>>(u, 0, wu2, bu2, out, d);
        }
    }
}

// Round 3
// 3718.574 us; speedup vs baseline: 1.0746x; 1.0746x over previous
//
#include <hip/hip_runtime.h>

#define DD 48
#define HF 256
#define WF 320
#define HH 128
#define WH 160
#define NPF (HF * WF)     // 81920
#define NPH (HH * WH)     // 20480
#define S1SZ (8 * NPF)    // one s1-class slice (floats)
#define S2SZ (16 * NPH)   // one s2-class slice (floats)

__device__ __forceinline__ float sigf(float x) { return 1.0f / (1.0f + __expf(-x)); }
__device__ __forceinline__ float tanh_(float x) {
    float e = __expf(2.0f * x);
    return 1.0f - 2.0f / (e + 1.0f);
}

// ---- 2-px conv core -------------------------------------------------------
template<int Ht, int Wt>
__device__ __forceinline__ void taps2(int y, int x0, int* off, float* msk) {
    int cx[4]; float cm[4];
    cx[0] = max(x0 - 1, 0);      cm[0] = (x0 > 0) ? 1.0f : 0.0f;
    cx[1] = x0;                  cm[1] = 1.0f;
    cx[2] = x0 + 1;              cm[2] = 1.0f;                      // x0+1 <= Wt-1 always
    cx[3] = min(x0 + 2, Wt - 1); cm[3] = (x0 + 2 < Wt) ? 1.0f : 0.0f;
#pragma unroll
    for (int r = 0; r < 3; ++r) {
        int yy = y - 1 + r;
        float rm = ((unsigned)yy < (unsigned)Ht) ? 1.0f : 0.0f;
        int rb = min(max(yy, 0), Ht - 1) * Wt;
#pragma unroll
        for (int k = 0; k < 4; ++k) {
            off[r * 4 + k] = rb + cx[k];
            msk[r * 4 + k] = rm * cm[k];
        }
    }
}

template<int CI, int COUT>
__device__ __forceinline__ void acc2px(
    const float* __restrict__ in, int cs,
    const float* __restrict__ w, int wcs,
    const int* off, const float* msk,
    float* a0, float* a1)
{
#pragma unroll 2
    for (int ci = 0; ci < CI; ++ci) {
        const float* p = in + ci * cs;
        float v[12];
#pragma unroll
        for (int k = 0; k < 12; ++k) v[k] = p[off[k]] * msk[k];
        const float* wp = w + ci * 9;
#pragma unroll
        for (int j = 0; j < COUT; ++j) {
            const float* wc = wp + j * wcs;
#pragma unroll
            for (int r = 0; r < 3; ++r) {
                a0[j] = fmaf(v[r * 4 + 0], wc[r * 3 + 0], a0[j]);
                a0[j] = fmaf(v[r * 4 + 1], wc[r * 3 + 1], a0[j]);
                a0[j] = fmaf(v[r * 4 + 2], wc[r * 3 + 2], a0[j]);
                a1[j] = fmaf(v[r * 4 + 1], wc[r * 3 + 0], a1[j]);
                a1[j] = fmaf(v[r * 4 + 2], wc[r * 3 + 1], a1[j]);
                a1[j] = fmaf(v[r * 4 + 3], wc[r * 3 + 2], a1[j]);
            }
        }
    }
}

// ---- conv1 role (batched/prologue): vertical 4-px strip per thread --------
__device__ __forceinline__ void conv1_role(
    const float* __restrict__ x, const float* __restrict__ w,
    const float* __restrict__ b, float* __restrict__ o_slice,
    int dsl, int pb)
{
    const int t = pb * 256 + threadIdx.x;   // [0, 20480) per slice
    const int xc = t % WF;
    const int yb = (t / WF) * 4;
    const float* __restrict__ xin = x + (long)dsl * NPF;
    const int cxm = max(xc - 1, 0), cxp = min(xc + 1, WF - 1);
    const float cmm = (xc > 0) ? 1.0f : 0.0f;
    const float cmp = (xc < WF - 1) ? 1.0f : 0.0f;
    int off[18]; float msk[18];
#pragma unroll
    for (int r = 0; r < 6; ++r) {
        const int yy = yb - 1 + r;
        const float rm = ((unsigned)yy < (unsigned)HF) ? 1.0f : 0.0f;
        const int rb = min(max(yy, 0), HF - 1) * WF;
        off[r * 3 + 0] = rb + cxm; msk[r * 3 + 0] = rm * cmm;
        off[r * 3 + 1] = rb + xc;  msk[r * 3 + 1] = rm;
        off[r * 3 + 2] = rb + cxp; msk[r * 3 + 2] = rm * cmp;
    }
    float acc[4][8];
#pragma unroll
    for (int j = 0; j < 8; ++j) {
        const float bj = b[j];
#pragma unroll
        for (int q = 0; q < 4; ++q) acc[q][j] = bj;
    }
#pragma unroll 2
    for (int ci = 0; ci < 32; ++ci) {
        const float* p = xin + (long)ci * (DD * NPF);
        float v[18];
#pragma unroll
        for (int k = 0; k < 18; ++k) v[k] = p[off[k]] * msk[k];
        const float* wp = w + ci * 9;                 // w (8,32,3,3): cout stride 288
#pragma unroll
        for (int j = 0; j < 8; ++j) {
            const float* wc = wp + j * (32 * 9);
#pragma unroll
            for (int q = 0; q < 4; ++q) {
#pragma unroll
                for (int r = 0; r < 3; ++r) {
                    acc[q][j] = fmaf(v[(q + r) * 3 + 0], wc[r * 3 + 0], acc[q][j]);
                    acc[q][j] = fmaf(v[(q + r) * 3 + 1], wc[r * 3 + 1], acc[q][j]);
                    acc[q][j] = fmaf(v[(q + r) * 3 + 2], wc[r * 3 + 2], acc[q][j]);
                }
            }
        }
    }
    float* o = o_slice + yb * WF + xc;
#pragma unroll
    for (int j = 0; j < 8; ++j)
#pragma unroll
        for (int q = 0; q < 4; ++q)
            o[j * NPF + q * WF] = fmaxf(acc[q][j], 0.0f);
}

// ---- conv1 role (chain-folded): 1 px per thread, 320 blocks/slice ---------
// Balanced to the gates roles: 8co x 9 x 32ci = 2304 FMA/thread.
__device__ __forceinline__ void conv1p_role(
    const float* __restrict__ x, const float* __restrict__ w,
    const float* __restrict__ b, float* __restrict__ o_slice,
    int dsl, int pb)
{
    const int t = pb * 256 + threadIdx.x;   // [0, NPF)
    const int y = t / WF, xc = t - y * WF;
    const float* __restrict__ xin = x + (long)dsl * NPF;
    const int cxm = max(xc - 1, 0), cxp = min(xc + 1, WF - 1);
    const float cmm = (xc > 0) ? 1.0f : 0.0f;
    const float cmp = (xc < WF - 1) ? 1.0f : 0.0f;
    int off[9]; float msk[9];
#pragma unroll
    for (int r = 0; r < 3; ++r) {
        const int yy = y - 1 + r;
        const float rm = ((unsigned)yy < (unsigned)HF) ? 1.0f : 0.0f;
        const int rb = min(max(yy, 0), HF - 1) * WF;
        off[r * 3 + 0] = rb + cxm; msk[r * 3 + 0] = rm * cmm;
        off[r * 3 + 1] = rb + xc;  msk[r * 3 + 1] = rm;
        off[r * 3 + 2] = rb + cxp; msk[r * 3 + 2] = rm * cmp;
    }
    float acc[8];
#pragma unroll
    for (int j = 0; j < 8; ++j) acc[j] = b[j];
#pragma unroll 2
    for (int ci = 0; ci < 32; ++ci) {
        const float* p = xin + (long)ci * (DD * NPF);
        float v[9];
#pragma unroll
        for (int k = 0; k < 9; ++k) v[k] = p[off[k]] * msk[k];
        const float* wp = w + ci * 9;                 // w (8,32,3,3): cout stride 288
#pragma unroll
        for (int j = 0; j < 8; ++j) {
            const float* wc = wp + j * (32 * 9);
#pragma unroll
            for (int k = 0; k < 9; ++k) acc[j] = fmaf(v[k], wc[k], acc[j]);
        }
    }
    float* o = o_slice + t;
#pragma unroll
    for (int j = 0; j < 8; ++j) o[j * NPF] = fmaxf(acc[j], 0.0f);
}

__global__ __launch_bounds__(256) void k_conv1(
    const float* __restrict__ x, const float* __restrict__ w,
    const float* __restrict__ b, float* __restrict__ out,
    int d0, int ostride)
{
    conv1_role(x, w, b, out + (long)blockIdx.z * ostride, d0 + blockIdx.z, blockIdx.x);
}

// ---- gates role -----------------------------------------------------------
template<int C, int Ht, int Wt, int CO>
__device__ __forceinline__ void gates_role(
    const float* __restrict__ a, const float* __restrict__ s,
    const float* __restrict__ w, const float* __restrict__ b,
    float* __restrict__ rh, float* __restrict__ u, int pb, int cog)
{
    constexpr int NP = Ht * Wt;
    const int pix0 = (pb * 256 + threadIdx.x) * 2;
    const int y = pix0 / Wt, x0 = pix0 - y * Wt;
    const int co0 = cog * CO;
    int off[12]; float msk[12];
    taps2<Ht, Wt>(y, x0, off, msk);
    float a0[CO], a1[CO];
#pragma unroll
    for (int j = 0; j < CO; ++j) { a0[j] = b[co0 + j]; a1[j] = b[co0 + j]; }
    acc2px<C, CO>(a, NP, w + co0 * (2 * C * 9), 2 * C * 9, off, msk, a0, a1);
    acc2px<C, CO>(s, NP, w + co0 * (2 * C * 9) + C * 9, 2 * C * 9, off, msk, a0, a1);
    if (co0 < C) {
#pragma unroll
        for (int j = 0; j < CO; ++j) {
            int o = (co0 + j) * NP + pix0;
            rh[o]     = sigf(a0[j]) * s[o];
            rh[o + 1] = sigf(a1[j]) * s[o + 1];
        }
    } else {
#pragma unroll
        for (int j = 0; j < CO; ++j) {
            int o = (co0 - C + j) * NP + pix0;
            u[o]     = sigf(a0[j]);
            u[o + 1] = sigf(a1[j]);
        }
    }
}

// ---- cand role ------------------------------------------------------------
template<int C, int Ht, int Wt, int CO>
__device__ __forceinline__ void cand_role(
    const float* __restrict__ a, const float* __restrict__ rh,
    const float* __restrict__ w, const float* __restrict__ b,
    const float* __restrict__ u, const float* __restrict__ sprev,
    float* __restrict__ sout, int pb, int cog)
{
    constexpr int NP = Ht * Wt;
    const int pix0 = (pb * 256 + threadIdx.x) * 2;
    const int y = pix0 / Wt, x0 = pix0 - y * Wt;
    const int co0 = cog * CO;
    int off[12]; float msk[12];
    taps2<Ht, Wt>(y, x0, off, msk);
    float a0[CO], a1[CO];
#pragma unroll
    for (int j = 0; j < CO; ++j) { a0[j] = b[co0 + j]; a1[j] = b[co0 + j]; }
    acc2px<C, CO>(a, NP, w + co0 * (2 * C * 9), 2 * C * 9, off, msk, a0, a1);
    acc2px<C, CO>(rh, NP, w + co0 * (2 * C * 9) + C * 9, 2 * C * 9, off, msk, a0, a1);
#pragma unroll
    for (int j = 0; j < CO; ++j) {
        int o = (co0 + j) * NP + pix0;
        float c0 = tanh_(a0[j]);
        float c1 = tanh_(a1[j]);
        sout[o]     = fmaf(u[o],     sprev[o]     - c0, c0);
        sout[o + 1] = fmaf(u[o + 1], sprev[o + 1] - c1, c1);
    }
}

// ---- conv2 role: stride-2 3x3 pad1, (8,HF,WF) -> relu -> (16,HH,WH) -------
__device__ __forceinline__ void conv2_role(
    const float* __restrict__ s1, const float* __restrict__ w,
    const float* __restrict__ b, float* __restrict__ c2, int pb, int cog)
{
    const int pix0 = (pb * 256 + threadIdx.x) * 2;  // output px in NPH
    const int y = pix0 / WH, x0 = pix0 - y * WH;    // x0 even, <= WH-2
    const int co0 = cog * 8;
    int off[15]; float msk[15];
    {
        int cx[5]; float cm[5];
        cx[0] = max(2 * x0 - 1, 0); cm[0] = (x0 > 0) ? 1.0f : 0.0f;
#pragma unroll
        for (int i = 1; i < 5; ++i) { cx[i] = 2 * x0 - 1 + i; cm[i] = 1.0f; }
#pragma unroll
        for (int r = 0; r < 3; ++r) {
            int yy = 2 * y - 1 + r;
            float rm = ((unsigned)yy < (unsigned)HF) ? 1.0f : 0.0f;
            int rb = min(max(yy, 0), HF - 1) * WF;
#pragma unroll
            for (int i = 0; i < 5; ++i) { off[r * 5 + i] = rb + cx[i]; msk[r * 5 + i] = rm * cm[i]; }
        }
    }
    float a0[8], a1[8];
#pragma unroll
    for (int j = 0; j < 8; ++j) { a0[j] = b[co0 + j]; a1[j] = b[co0 + j]; }
#pragma unroll 2
    for (int ci = 0; ci < 8; ++ci) {
        const float* p = s1 + ci * NPF;
        float v[15];
#pragma unroll
        for (int k = 0; k < 15; ++k) v[k] = p[off[k]] * msk[k];
        const float* wp = w + co0 * 72 + ci * 9;   // w (16,8,3,3), cout stride 72
#pragma unroll
        for (int j = 0; j < 8; ++j) {
            const float* wc = wp + j * 72;
#pragma unroll
            for (int r = 0; r < 3; ++r) {
                a0[j] = fmaf(v[r * 5 + 0], wc[r * 3 + 0], a0[j]);
                a0[j] = fmaf(v[r * 5 + 1], wc[r * 3 + 1], a0[j]);
                a0[j] = fmaf(v[r * 5 + 2], wc[r * 3 + 2], a0[j]);
                a1[j] = fmaf(v[r * 5 + 2], wc[r * 3 + 0], a1[j]);
                a1[j] = fmaf(v[r * 5 + 3], wc[r * 3 + 1], a1[j]);
                a1[j] = fmaf(v[r * 5 + 4], wc[r * 3 + 2], a1[j]);
            }
        }
    }
#pragma unroll
    for (int j = 0; j < 8; ++j) {
        c2[(co0 + j) * NPH + pix0]     = fmaxf(a0[j], 0.0f);
        c2[(co0 + j) * NPH + pix0 + 1] = fmaxf(a1[j], 0.0f);
    }
}

// ---- up1 role: ConvTranspose2d(16->8,k3,s2,p1,op1) + s1 skip + relu -------
__device__ __forceinline__ void up1_role(
    const float* __restrict__ s2, const float* __restrict__ w,
    const float* __restrict__ b, const float* __restrict__ s1,
    float* __restrict__ ubuf, int pb)
{
    const int q = pb * 256 + threadIdx.x;  // < NPH
    const int r = q / WH, c = q - r * WH;
    const int dc = (c + 1 < WH) ? 1 : 0;
    const int dr = (r + 1 < HH) ? WH : 0;
    const float mc = (c + 1 < WH) ? 1.0f : 0.0f;
    const float mr = (r + 1 < HH) ? 1.0f : 0.0f;
    const float mrc = mc * mr;
    float a00[8], a01[8], a10[8], a11[8];
#pragma unroll
    for (int j = 0; j < 8; ++j) { a00[j] = b[j]; a01[j] = b[j]; a10[j] = b[j]; a11[j] = b[j]; }
#pragma unroll 2
    for (int ci = 0; ci < 16; ++ci) {
        const float* p = s2 + ci * NPH + r * WH + c;
        float v00 = p[0];
        float v01 = p[dc] * mc;
        float v10 = p[dr] * mr;
        float v11 = p[dr + dc] * mrc;
        const float* wp = w + ci * 8 * 9;
#pragma unroll
        for (int j = 0; j < 8; ++j) {
            const float* wc = wp + j * 9;
            a00[j] = fmaf(v00, wc[4], a00[j]);
            a01[j] = fmaf(v01, wc[3], fmaf(v00, wc[5], a01[j]));
            a10[j] = fmaf(v10, wc[1], fmaf(v00, wc[7], a10[j]));
            a11[j] = fmaf(v11, wc[0], fmaf(v10, wc[2], fmaf(v01, wc[6], fmaf(v00, wc[8], a11[j]))));
        }
    }
    const int o0 = (2 * r) * WF + 2 * c;
#pragma unroll
    for (int j = 0; j < 8; ++j) {
        int o = j * NPF + o0;
        ubuf[o]          = fmaxf(a00[j] + s1[o], 0.0f);
        ubuf[o + 1]      = fmaxf(a01[j] + s1[o + 1], 0.0f);
        ubuf[o + WF]     = fmaxf(a10[j] + s1[o + WF], 0.0f);
        ubuf[o + WF + 1] = fmaxf(a11[j] + s1[o + WF + 1], 0.0f);
    }
}

// ---- up2 role: ConvTranspose2d(8->1,k3,s2,p1,op1) -> out slice (512,640) --
__device__ __forceinline__ void up2_role(
    const float* __restrict__ u, const float* __restrict__ w,
    const float* __restrict__ b, float* __restrict__ oslice, int pb)
{
    const int q = pb * 256 + threadIdx.x;  // < NPF
    const int r = q / WF, c = q - r * WF;
    const int dc = (c + 1 < WF) ? 1 : 0;
    const int dr = (r + 1 < HF) ? WF : 0;
    const float mc = (c + 1 < WF) ? 1.0f : 0.0f;
    const float mr = (r + 1 < HF) ? 1.0f : 0.0f;
    const float mrc = mc * mr;
    const float b0 = b[0];
    float a00 = b0, a01 = b0, a10 = b0, a11 = b0;
#pragma unroll 2
    for (int ci = 0; ci < 8; ++ci) {
        const float* p = u + ci * NPF + r * WF + c;
        float v00 = p[0];
        float v01 = p[dc] * mc;
        float v10 = p[dr] * mr;
        float v11 = p[dr + dc] * mrc;
        const float* wc = w + ci * 9;
        a00 = fmaf(v00, wc[4], a00);
        a01 = fmaf(v01, wc[3], fmaf(v00, wc[5], a01));
        a10 = fmaf(v10, wc[1], fmaf(v00, wc[7], a10));
        a11 = fmaf(v11, wc[0], fmaf(v10, wc[2], fmaf(v01, wc[6], fmaf(v00, wc[8], a11))));
    }
    float* o = oslice + (2 * r) * 640 + 2 * c;
    o[0] = a00; o[1] = a01; o[640] = a10; o[641] = a11;
}

// ---- fused skewed-chain steps ---------------------------------------------
// A(d): gates1(d) [0,320) | gates2(d-2) [320,640) | conv1(d+2) [640,960) |
//       up1(d-3) [960,1040)   -- all heavy roles balanced at 2304 FMA/thread
__global__ __launch_bounds__(256) void k_stepA(
    const float* __restrict__ x, const float* __restrict__ w1,
    const float* __restrict__ b1, float* __restrict__ c1_all,
    const float* __restrict__ s1_all,
    const float* __restrict__ wg1, const float* __restrict__ bg1,
    float* __restrict__ rh1, float* __restrict__ ug1,
    const float* __restrict__ c2_all, const float* __restrict__ s2_all,
    const float* __restrict__ wg2, const float* __restrict__ bg2,
    float* __restrict__ rh2, float* __restrict__ ug2,
    const float* __restrict__ wu1, const float* __restrict__ bu1,
    float* __restrict__ ubuf,
    int d1, int d2, int dcv1, int du1)
{
    const int bid = blockIdx.x;
    if (bid < 320) {
        if (d1 < 0) return;
        gates_role<8, HF, WF, 8>(c1_all + (long)d1 * S1SZ, s1_all + (long)d1 * S1SZ,
                                 wg1, bg1, rh1, ug1, bid % 160, bid / 160);
    } else if (bid < 640) {
        if (d2 < 0) return;
        const int bb = bid - 320;
        gates_role<16, HH, WH, 4>(c2_all + (long)d2 * S2SZ, s2_all + (long)d2 * S2SZ,
                                  wg2, bg2, rh2, ug2, bb % 40, bb / 40);
    } else if (bid < 960) {
        if (dcv1 < 0) return;
        conv1p_role(x, w1, b1, c1_all + (long)dcv1 * S1SZ, dcv1, bid - 640);
    } else {
        if (du1 < 0) return;
        up1_role(s2_all + (long)(du1 + 1) * S2SZ, wu1, bu1,
                 s1_all + (long)(du1 + 1) * S1SZ, ubuf, bid - 960);
    }
}

// B(d): cand1(d) [0,160) | conv2(d-1) [160,240) | cand2(d-2) [240,400) |
//       up2(d-3) [400,720)
__global__ __launch_bounds__(256) void k_stepB(
    const float* __restrict__ c1_all, float* __restrict__ s1_all,
    const float* __restrict__ wc1, const float* __restrict__ bc1,
    const float* __restrict__ rh1, const float* __restrict__ ug1,
    const float* __restrict__ w2, const float* __restrict__ b2,
    float* __restrict__ c2_all, float* __restrict__ s2_all,
    const float* __restrict__ wc2, const float* __restrict__ bc2,
    const float* __restrict__ rh2, const float* __restrict__ ug2,
    const float* __restrict__ wu2, const float* __restrict__ bu2,
    const float* __restrict__ ubuf, float* __restrict__ out,
    int d1, int dc, int d2, int du2)
{
    const int bid = blockIdx.x;
    if (bid < 160) {
        if (d1 < 0) return;
        cand_role<8, HF, WF, 8>(c1_all + (long)d1 * S1SZ, rh1, wc1, bc1, ug1,
                                s1_all + (long)d1 * S1SZ, s1_all + (long)(d1 + 1) * S1SZ,
                                bid, 0);
    } else if (bid < 240) {
        if (dc < 0) return;
        const int bb = bid - 160;
        conv2_role(s1_all + (long)(dc + 1) * S1SZ, w2, b2,
                   c2_all + (long)dc * S2SZ, bb % 40, bb / 40);
    } else if (bid < 400) {
        if (d2 < 0) return;
        const int bb = bid - 240;
        cand_role<16, HH, WH, 4>(c2_all + (long)d2 * S2SZ, rh2, wc2, bc2, ug2,
                                 s2_all + (long)d2 * S2SZ, s2_all + (long)(d2 + 1) * S2SZ,
                                 bb % 40, bb / 40);
    } else {
        if (du2 < 0) return;
        up2_role(ubuf, wu2, bu2, out + (long)du2 * (512 * 640), bid - 400);
    }
}

// ---- standalone wrappers (fallback path) ----------------------------------
template<int C, int Ht, int Wt, int CO>
__global__ __launch_bounds__(256) void k_gates(
    const float* __restrict__ a, const float* __restrict__ s,
    const float* __restrict__ w, const float* __restrict__ b,
    float* __restrict__ rh, float* __restrict__ u)
{ gates_role<C, Ht, Wt, CO>(a, s, w, b, rh, u, blockIdx.x, blockIdx.y); }

template<int C, int Ht, int Wt, int CO>
__global__ __launch_bounds__(256) void k_cand(
    const float* __restrict__ a, const float* __restrict__ rh,
    const float* __restrict__ w, const float* __restrict__ b,
    const float* __restrict__ u, const float* __restrict__ sprev,
    float* __restrict__ sout)
{ cand_role<C, Ht, Wt, CO>(a, rh, w, b, u, sprev, sout, blockIdx.x, blockIdx.y); }

__global__ __launch_bounds__(256) void k_conv2w(
    const float* __restrict__ s1, const float* __restrict__ w,
    const float* __restrict__ b, float* __restrict__ c2)
{ conv2_role(s1, w, b, c2, blockIdx.x, blockIdx.y); }

__global__ __launch_bounds__(256) void k_up1(
    const float* __restrict__ s2b, int zs2,
    const float* __restrict__ w, const float* __restrict__ b,
    const float* __restrict__ s1b, int zs1,
    float* __restrict__ ub, int zu)
{
    up1_role(s2b + (long)blockIdx.z * zs2, w, b,
             s1b + (long)blockIdx.z * zs1, ub + (long)blockIdx.z * zu, blockIdx.x);
}

__global__ __launch_bounds__(256) void k_up2(
    const float* __restrict__ ub, int zu,
    const float* __restrict__ w, const float* __restrict__ b,
    float* __restrict__ out, int d0)
{
    up2_role(ub + (long)blockIdx.z * zu, w, b,
             out + (long)(d0 + blockIdx.z) * (512 * 640), blockIdx.x);
}

extern "C" void kernel_launch(void* const* d_in, const int* in_sizes, int n_in,
                              void* d_out, int out_size, void* d_ws, size_t ws_size,
                              hipStream_t stream)
{
    const float* x   = (const float*)d_in[0];
    const float* w1  = (const float*)d_in[1];
    const float* b1  = (const float*)d_in[2];
    const float* wg1 = (const float*)d_in[3];
    const float* bg1 = (const float*)d_in[4];
    const float* wc1 = (const float*)d_in[5];
    const float* bc1 = (const float*)d_in[6];
    const float* w2  = (const float*)d_in[7];
    const float* b2  = (const float*)d_in[8];
    const float* wg2 = (const float*)d_in[9];
    const float* bg2 = (const float*)d_in[10];
    const float* wc2 = (const float*)d_in[11];
    const float* bc2 = (const float*)d_in[12];
    const float* wu1 = (const float*)d_in[13];
    const float* bu1 = (const float*)d_in[14];
    const float* wu2 = (const float*)d_in[15];
    const float* bu2 = (const float*)d_in[16];
    float* out = (float*)d_out;
    float* ws = (float*)d_ws;

    // ---- full-history schedule: skewed fused chains + balanced fold ----
    {
        float* p = ws;
        float* s1_all = p; p += 49L * S1SZ;   // slice 0 = zeros
        float* s2_all = p; p += 49L * S2SZ;
        float* c2_all = p; p += 48L * S2SZ;
        float* rh1 = p; p += S1SZ;
        float* ug1 = p; p += S1SZ;
        float* rh2 = p; p += S2SZ;
        float* ug2 = p; p += S2SZ;
        float* ubuf = p; p += S1SZ;           // single up1->up2 slice (A(d)->B(d))
        float* c1_all = p; p += 48L * S1SZ;
        const size_t need = (size_t)(p - ws) * sizeof(float);
        if (ws_size >= need) {
            hipMemsetAsync(s1_all, 0, (size_t)S1SZ * sizeof(float), stream);
            hipMemsetAsync(s2_all, 0, (size_t)S2SZ * sizeof(float), stream);

            // Prologue: conv1 for slices 0,1 (chain folds in slice d+2).
            k_conv1<<<dim3(80, 1, 2), 256, 0, stream>>>(x, w1, b1, c1_all, 0, S1SZ);
            // Skew (all producers >= 1 dispatch ahead of consumers):
            //   A(d): gates1(d) | gates2(d-2) | conv1(d+2) | up1(d-3)
            //   B(d): cand1(d) | conv2(d-1) | cand2(d-2) | up2(d-3)
            for (int d = 0; d <= 50; ++d) {
                const int g1  = (d < 48) ? d : -1;
                const int g2  = (d >= 2 && d <= 49) ? d - 2 : -1;
                const int cv1 = (d + 2 < 48) ? d + 2 : -1;
                const int u1  = (d >= 3) ? d - 3 : -1;          // <= 47 since d <= 50
                const int cv  = (d >= 1 && d <= 48) ? d - 1 : -1;
                k_stepA<<<dim3(1040), 256, 0, stream>>>(
                    x, w1, b1, c1_all, s1_all, wg1, bg1, rh1, ug1,
                    c2_all, s2_all, wg2, bg2, rh2, ug2,
                    wu1, bu1, ubuf, g1, g2, cv1, u1);
                k_stepB<<<dim3(720), 256, 0, stream>>>(
                    c1_all, s1_all, wc1, bc1, rh1, ug1,
                    w2, b2, c2_all, s2_all, wc2, bc2, rh2, ug2,
                    wu2, bu2, ubuf, out, g1, cv, g2, u1);
            }
            return;
        }
    }

    // ---- fallback: small-workspace interleaved schedule ----
    {
        float* p = ws;
        float* s1 = p; p += S1SZ;
        float* s2 = p; p += S2SZ;
        float* rh1 = p; p += S1SZ;
        float* ug1 = p; p += S1SZ;
        float* c2 = p; p += S2SZ;
        float* rh2 = p; p += S2SZ;
        float* ug2 = p; p += S2SZ;
        float* c1 = p; p += S1SZ;
        float* u = p; p += S1SZ;
        hipMemsetAsync(s1, 0, (size_t)S1SZ * sizeof(float), stream);
        hipMemsetAsync(s2, 0, (size_t)S2SZ * sizeof(float), stream);
        for (int d = 0; d < 48; ++d) {
            k_conv1<<<dim3(80, 1, 1), 256, 0, stream>>>(x, w1, b1, c1, d, 0);
            k_gates<8, HF, WF, 8><<<dim3(160, 2), 256, 0, stream>>>(c1, s1, wg1, bg1, rh1, ug1);
            k_cand <8, HF, WF, 8><<<dim3(160, 1), 256, 0, stream>>>(c1, rh1, wc1, bc1, ug1, s1, s1);
            k_conv2w<<<dim3(40, 2), 256, 0, stream>>>(s1, w2, b2, c2);
            k_gates<16, HH, WH, 8><<<dim3(40, 4), 256, 0, stream>>>(c2, s2, wg2, bg2, rh2, ug2);
            k_cand <16, HH, WH, 8><<<dim3(40, 2), 256, 0, stream>>>(c2, rh2, wc2, bc2, ug2, s2, s2);
            k_up1<<<dim3(80, 1, 1), 256, 0, stream>>>(s2, 0, wu1, bu1, s1, 0, u, 0);
            k_up2<<<dim3(320, 1, 1), 256, 0, stream>>>(u, 0, wu2, bu2, out, d);
        }
    }
}

// Round 4
// 3148.444 us; speedup vs baseline: 1.2692x; 1.1811x over previous
//
#include <hip/hip_runtime.h>

#define DD 48
#define HF 256
#define WF 320
#define HH 128
#define WH 160
#define NPF (HF * WF)     // 81920
#define NPH (HH * WH)     // 20480
#define S1SZ (8 * NPF)    // one s1-class slice (floats)
#define S2SZ (16 * NPH)   // one s2-class slice (floats)

__device__ __forceinline__ float sigf(float x) { return 1.0f / (1.0f + __expf(-x)); }
__device__ __forceinline__ float tanh_(float x) {
    float e = __expf(2.0f * x);
    return 1.0f - 2.0f / (e + 1.0f);
}

// ---- vertical 2-px conv core ----------------------------------------------
// Thread computes output pixels (y0, x) and (y0+1, x); lanes are consecutive
// in x => every tap load/store is dense 4B/lane (4 cache lines per wave op).
// Taps: 4 rows x 3 cols = 12 clamped+masked loads per input channel.

template<int Ht, int Wt>
__device__ __forceinline__ void taps2v(int y0, int x, int* off, float* msk) {
    const int xm = max(x - 1, 0), xp = min(x + 1, Wt - 1);
    const float cm0 = (x > 0) ? 1.0f : 0.0f;
    const float cm2 = (x < Wt - 1) ? 1.0f : 0.0f;
#pragma unroll
    for (int r = 0; r < 4; ++r) {
        const int yy = y0 - 1 + r;
        const float rm = ((unsigned)yy < (unsigned)Ht) ? 1.0f : 0.0f;
        const int rb = min(max(yy, 0), Ht - 1) * Wt;
        off[r * 3 + 0] = rb + xm; msk[r * 3 + 0] = rm * cm0;
        off[r * 3 + 1] = rb + x;  msk[r * 3 + 1] = rm;
        off[r * 3 + 2] = rb + xp; msk[r * 3 + 2] = rm * cm2;
    }
}

// acc 2 vertical px x COUT over CI channels. a0 = row y0 (v rows 0..2),
// a1 = row y0+1 (v rows 1..3).
template<int CI, int COUT>
__device__ __forceinline__ void acc2v(
    const float* __restrict__ in, int cs,
    const float* __restrict__ w, int wcs,
    const int* off, const float* msk,
    float* a0, float* a1)
{
#pragma unroll 2
    for (int ci = 0; ci < CI; ++ci) {
        const float* p = in + ci * cs;
        float v[12];
#pragma unroll
        for (int k = 0; k < 12; ++k) v[k] = p[off[k]] * msk[k];
        const float* wp = w + ci * 9;
#pragma unroll
        for (int j = 0; j < COUT; ++j) {
            const float* wc = wp + j * wcs;
#pragma unroll
            for (int r = 0; r < 3; ++r) {
#pragma unroll
                for (int c = 0; c < 3; ++c) {
                    a0[j] = fmaf(v[r * 3 + c],       wc[r * 3 + c], a0[j]);
                    a1[j] = fmaf(v[(r + 1) * 3 + c], wc[r * 3 + c], a1[j]);
                }
            }
        }
    }
}

// ---- conv1 role (batched/prologue): vertical 4-px strip per thread --------
__device__ __forceinline__ void conv1_role(
    const float* __restrict__ x, const float* __restrict__ w,
    const float* __restrict__ b, float* __restrict__ o_slice,
    int dsl, int pb)
{
    const int t = pb * 256 + threadIdx.x;   // [0, 20480) per slice
    const int xc = t % WF;
    const int yb = (t / WF) * 4;
    const float* __restrict__ xin = x + (long)dsl * NPF;
    const int cxm = max(xc - 1, 0), cxp = min(xc + 1, WF - 1);
    const float cmm = (xc > 0) ? 1.0f : 0.0f;
    const float cmp = (xc < WF - 1) ? 1.0f : 0.0f;
    int off[18]; float msk[18];
#pragma unroll
    for (int r = 0; r < 6; ++r) {
        const int yy = yb - 1 + r;
        const float rm = ((unsigned)yy < (unsigned)HF) ? 1.0f : 0.0f;
        const int rb = min(max(yy, 0), HF - 1) * WF;
        off[r * 3 + 0] = rb + cxm; msk[r * 3 + 0] = rm * cmm;
        off[r * 3 + 1] = rb + xc;  msk[r * 3 + 1] = rm;
        off[r * 3 + 2] = rb + cxp; msk[r * 3 + 2] = rm * cmp;
    }
    float acc[4][8];
#pragma unroll
    for (int j = 0; j < 8; ++j) {
        const float bj = b[j];
#pragma unroll
        for (int q = 0; q < 4; ++q) acc[q][j] = bj;
    }
#pragma unroll 2
    for (int ci = 0; ci < 32; ++ci) {
        const float* p = xin + (long)ci * (DD * NPF);
        float v[18];
#pragma unroll
        for (int k = 0; k < 18; ++k) v[k] = p[off[k]] * msk[k];
        const float* wp = w + ci * 9;                 // w (8,32,3,3): cout stride 288
#pragma unroll
        for (int j = 0; j < 8; ++j) {
            const float* wc = wp + j * (32 * 9);
#pragma unroll
            for (int q = 0; q < 4; ++q) {
#pragma unroll
                for (int r = 0; r < 3; ++r) {
                    acc[q][j] = fmaf(v[(q + r) * 3 + 0], wc[r * 3 + 0], acc[q][j]);
                    acc[q][j] = fmaf(v[(q + r) * 3 + 1], wc[r * 3 + 1], acc[q][j]);
                    acc[q][j] = fmaf(v[(q + r) * 3 + 2], wc[r * 3 + 2], acc[q][j]);
                }
            }
        }
    }
    float* o = o_slice + yb * WF + xc;
#pragma unroll
    for (int j = 0; j < 8; ++j)
#pragma unroll
        for (int q = 0; q < 4; ++q)
            o[j * NPF + q * WF] = fmaxf(acc[q][j], 0.0f);
}

// ---- conv1 role (chain-folded): 1 px per thread, 320 blocks/slice ---------
__device__ __forceinline__ void conv1p_role(
    const float* __restrict__ x, const float* __restrict__ w,
    const float* __restrict__ b, float* __restrict__ o_slice,
    int dsl, int pb)
{
    const int t = pb * 256 + threadIdx.x;   // [0, NPF)
    const int y = t / WF, xc = t - y * WF;
    const float* __restrict__ xin = x + (long)dsl * NPF;
    const int cxm = max(xc - 1, 0), cxp = min(xc + 1, WF - 1);
    const float cmm = (xc > 0) ? 1.0f : 0.0f;
    const float cmp = (xc < WF - 1) ? 1.0f : 0.0f;
    int off[9]; float msk[9];
#pragma unroll
    for (int r = 0; r < 3; ++r) {
        const int yy = y - 1 + r;
        const float rm = ((unsigned)yy < (unsigned)HF) ? 1.0f : 0.0f;
        const int rb = min(max(yy, 0), HF - 1) * WF;
        off[r * 3 + 0] = rb + cxm; msk[r * 3 + 0] = rm * cmm;
        off[r * 3 + 1] = rb + xc;  msk[r * 3 + 1] = rm;
        off[r * 3 + 2] = rb + cxp; msk[r * 3 + 2] = rm * cmp;
    }
    float acc[8];
#pragma unroll
    for (int j = 0; j < 8; ++j) acc[j] = b[j];
#pragma unroll 2
    for (int ci = 0; ci < 32; ++ci) {
        const float* p = xin + (long)ci * (DD * NPF);
        float v[9];
#pragma unroll
        for (int k = 0; k < 9; ++k) v[k] = p[off[k]] * msk[k];
        const float* wp = w + ci * 9;                 // w (8,32,3,3): cout stride 288
#pragma unroll
        for (int j = 0; j < 8; ++j) {
            const float* wc = wp + j * (32 * 9);
#pragma unroll
            for (int k = 0; k < 9; ++k) acc[j] = fmaf(v[k], wc[k], acc[j]);
        }
    }
    float* o = o_slice + t;
#pragma unroll
    for (int j = 0; j < 8; ++j) o[j * NPF] = fmaxf(acc[j], 0.0f);
}

__global__ __launch_bounds__(256) void k_conv1(
    const float* __restrict__ x, const float* __restrict__ w,
    const float* __restrict__ b, float* __restrict__ out,
    int d0, int ostride)
{
    conv1_role(x, w, b, out + (long)blockIdx.z * ostride, d0 + blockIdx.z, blockIdx.x);
}

// ---- gates role (vertical 2px) --------------------------------------------
template<int C, int Ht, int Wt, int CO>
__device__ __forceinline__ void gates_role(
    const float* __restrict__ a, const float* __restrict__ s,
    const float* __restrict__ w, const float* __restrict__ b,
    float* __restrict__ rh, float* __restrict__ u, int pb, int cog)
{
    constexpr int NP = Ht * Wt;
    const int t = pb * 256 + threadIdx.x;           // [0, NP/2)
    const int x = t % Wt, y0 = (t / Wt) * 2;
    const int co0 = cog * CO;
    int off[12]; float msk[12];
    taps2v<Ht, Wt>(y0, x, off, msk);
    float a0[CO], a1[CO];
#pragma unroll
    for (int j = 0; j < CO; ++j) { a0[j] = b[co0 + j]; a1[j] = b[co0 + j]; }
    acc2v<C, CO>(a, NP, w + co0 * (2 * C * 9), 2 * C * 9, off, msk, a0, a1);
    acc2v<C, CO>(s, NP, w + co0 * (2 * C * 9) + C * 9, 2 * C * 9, off, msk, a0, a1);
    const int p0 = y0 * Wt + x;
    if (co0 < C) {
#pragma unroll
        for (int j = 0; j < CO; ++j) {
            int o = (co0 + j) * NP + p0;
            rh[o]      = sigf(a0[j]) * s[o];
            rh[o + Wt] = sigf(a1[j]) * s[o + Wt];
        }
    } else {
#pragma unroll
        for (int j = 0; j < CO; ++j) {
            int o = (co0 - C + j) * NP + p0;
            u[o]      = sigf(a0[j]);
            u[o + Wt] = sigf(a1[j]);
        }
    }
}

// ---- cand role (vertical 2px) ---------------------------------------------
template<int C, int Ht, int Wt, int CO>
__device__ __forceinline__ void cand_role(
    const float* __restrict__ a, const float* __restrict__ rh,
    const float* __restrict__ w, const float* __restrict__ b,
    const float* __restrict__ u, const float* __restrict__ sprev,
    float* __restrict__ sout, int pb, int cog)
{
    constexpr int NP = Ht * Wt;
    const int t = pb * 256 + threadIdx.x;           // [0, NP/2)
    const int x = t % Wt, y0 = (t / Wt) * 2;
    const int co0 = cog * CO;
    int off[12]; float msk[12];
    taps2v<Ht, Wt>(y0, x, off, msk);
    float a0[CO], a1[CO];
#pragma unroll
    for (int j = 0; j < CO; ++j) { a0[j] = b[co0 + j]; a1[j] = b[co0 + j]; }
    acc2v<C, CO>(a, NP, w + co0 * (2 * C * 9), 2 * C * 9, off, msk, a0, a1);
    acc2v<C, CO>(rh, NP, w + co0 * (2 * C * 9) + C * 9, 2 * C * 9, off, msk, a0, a1);
    const int p0 = y0 * Wt + x;
#pragma unroll
    for (int j = 0; j < CO; ++j) {
        int o = (co0 + j) * NP + p0;
        float c0 = tanh_(a0[j]);
        float c1 = tanh_(a1[j]);
        sout[o]      = fmaf(u[o],      sprev[o]      - c0, c0);
        sout[o + Wt] = fmaf(u[o + Wt], sprev[o + Wt] - c1, c1);
    }
}

// ---- conv2 role (vertical 2px out): stride-2 3x3 pad1 ---------------------
// Out (y0,x),(y0+1,x), y0=2*yp; input rows 4yp-1..4yp+3 (5) x cols 2x-1..2x+1.
__device__ __forceinline__ void conv2_role(
    const float* __restrict__ s1, const float* __restrict__ w,
    const float* __restrict__ b, float* __restrict__ c2, int pb, int cog)
{
    const int t = pb * 256 + threadIdx.x;           // [0, NPH/2)
    const int x = t % WH, yp = t / WH;              // yp in [0, HH/2)
    const int y0 = 2 * yp;
    const int co0 = cog * 8;
    int off[15]; float msk[15];
    {
        const int cxm = max(2 * x - 1, 0);
        const float cmm = (x > 0) ? 1.0f : 0.0f;
#pragma unroll
        for (int r = 0; r < 5; ++r) {
            const int yy = 4 * yp - 1 + r;          // <= 4*(HH/2-1)+3 = HF-1
            const float rm = (yy >= 0) ? 1.0f : 0.0f;
            const int rb = max(yy, 0) * WF;
            off[r * 3 + 0] = rb + cxm;       msk[r * 3 + 0] = rm * cmm;
            off[r * 3 + 1] = rb + 2 * x;     msk[r * 3 + 1] = rm;
            off[r * 3 + 2] = rb + 2 * x + 1; msk[r * 3 + 2] = rm;   // 2x+1 <= WF-1
        }
    }
    float a0[8], a1[8];
#pragma unroll
    for (int j = 0; j < 8; ++j) { a0[j] = b[co0 + j]; a1[j] = b[co0 + j]; }
#pragma unroll 2
    for (int ci = 0; ci < 8; ++ci) {
        const float* p = s1 + ci * NPF;
        float v[15];
#pragma unroll
        for (int k = 0; k < 15; ++k) v[k] = p[off[k]] * msk[k];
        const float* wp = w + co0 * 72 + ci * 9;   // w (16,8,3,3), cout stride 72
#pragma unroll
        for (int j = 0; j < 8; ++j) {
            const float* wc = wp + j * 72;
#pragma unroll
            for (int r = 0; r < 3; ++r) {
#pragma unroll
                for (int c = 0; c < 3; ++c) {
                    a0[j] = fmaf(v[r * 3 + c],       wc[r * 3 + c], a0[j]);
                    a1[j] = fmaf(v[(r + 2) * 3 + c], wc[r * 3 + c], a1[j]);
                }
            }
        }
    }
    const int p0 = y0 * WH + x;
#pragma unroll
    for (int j = 0; j < 8; ++j) {
        c2[(co0 + j) * NPH + p0]      = fmaxf(a0[j], 0.0f);
        c2[(co0 + j) * NPH + p0 + WH] = fmaxf(a1[j], 0.0f);
    }
}

// ---- up1 role: ConvTranspose2d(16->8,k3,s2,p1,op1) + s1 skip + relu -------
__device__ __forceinline__ void up1_role(
    const float* __restrict__ s2, const float* __restrict__ w,
    const float* __restrict__ b, const float* __restrict__ s1,
    float* __restrict__ ubuf, int pb)
{
    const int q = pb * 256 + threadIdx.x;  // < NPH
    const int r = q / WH, c = q - r * WH;
    const int dc = (c + 1 < WH) ? 1 : 0;
    const int dr = (r + 1 < HH) ? WH : 0;
    const float mc = (c + 1 < WH) ? 1.0f : 0.0f;
    const float mr = (r + 1 < HH) ? 1.0f : 0.0f;
    const float mrc = mc * mr;
    float a00[8], a01[8], a10[8], a11[8];
#pragma unroll
    for (int j = 0; j < 8; ++j) { a00[j] = b[j]; a01[j] = b[j]; a10[j] = b[j]; a11[j] = b[j]; }
#pragma unroll 2
    for (int ci = 0; ci < 16; ++ci) {
        const float* p = s2 + ci * NPH + r * WH + c;
        float v00 = p[0];
        float v01 = p[dc] * mc;
        float v10 = p[dr] * mr;
        float v11 = p[dr + dc] * mrc;
        const float* wp = w + ci * 8 * 9;
#pragma unroll
        for (int j = 0; j < 8; ++j) {
            const float* wc = wp + j * 9;
            a00[j] = fmaf(v00, wc[4], a00[j]);
            a01[j] = fmaf(v01, wc[3], fmaf(v00, wc[5], a01[j]));
            a10[j] = fmaf(v10, wc[1], fmaf(v00, wc[7], a10[j]));
            a11[j] = fmaf(v11, wc[0], fmaf(v10, wc[2], fmaf(v01, wc[6], fmaf(v00, wc[8], a11[j]))));
        }
    }
    const int o0 = (2 * r) * WF + 2 * c;
#pragma unroll
    for (int j = 0; j < 8; ++j) {
        int o = j * NPF + o0;
        ubuf[o]          = fmaxf(a00[j] + s1[o], 0.0f);
        ubuf[o + 1]      = fmaxf(a01[j] + s1[o + 1], 0.0f);
        ubuf[o + WF]     = fmaxf(a10[j] + s1[o + WF], 0.0f);
        ubuf[o + WF + 1] = fmaxf(a11[j] + s1[o + WF + 1], 0.0f);
    }
}

// ---- up2 role: ConvTranspose2d(8->1,k3,s2,p1,op1) -> out slice (512,640) --
__device__ __forceinline__ void up2_role(
    const float* __restrict__ u, const float* __restrict__ w,
    const float* __restrict__ b, float* __restrict__ oslice, int pb)
{
    const int q = pb * 256 + threadIdx.x;  // < NPF
    const int r = q / WF, c = q - r * WF;
    const int dc = (c + 1 < WF) ? 1 : 0;
    const int dr = (r + 1 < HF) ? WF : 0;
    const float mc = (c + 1 < WF) ? 1.0f : 0.0f;
    const float mr = (r + 1 < HF) ? 1.0f : 0.0f;
    const float mrc = mc * mr;
    const float b0 = b[0];
    float a00 = b0, a01 = b0, a10 = b0, a11 = b0;
#pragma unroll 2
    for (int ci = 0; ci < 8; ++ci) {
        const float* p = u + ci * NPF + r * WF + c;
        float v00 = p[0];
        float v01 = p[dc] * mc;
        float v10 = p[dr] * mr;
        float v11 = p[dr + dc] * mrc;
        const float* wc = w + ci * 9;
        a00 = fmaf(v00, wc[4], a00);
        a01 = fmaf(v01, wc[3], fmaf(v00, wc[5], a01));
        a10 = fmaf(v10, wc[1], fmaf(v00, wc[7], a10));
        a11 = fmaf(v11, wc[0], fmaf(v10, wc[2], fmaf(v01, wc[6], fmaf(v00, wc[8], a11))));
    }
    float* o = oslice + (2 * r) * 640 + 2 * c;
    o[0] = a00; o[1] = a01; o[640] = a10; o[641] = a11;
}

// ---- fused skewed-chain steps ---------------------------------------------
// A(d): gates1(d) [0,320) | gates2(d-2) [320,640) | conv1(d+2) [640,960) |
//       up1(d-3) [960,1040)   -- heavy roles balanced at 2304 FMA/thread
__global__ __launch_bounds__(256) void k_stepA(
    const float* __restrict__ x, const float* __restrict__ w1,
    const float* __restrict__ b1, float* __restrict__ c1_all,
    const float* __restrict__ s1_all,
    const float* __restrict__ wg1, const float* __restrict__ bg1,
    float* __restrict__ rh1, float* __restrict__ ug1,
    const float* __restrict__ c2_all, const float* __restrict__ s2_all,
    const float* __restrict__ wg2, const float* __restrict__ bg2,
    float* __restrict__ rh2, float* __restrict__ ug2,
    const float* __restrict__ wu1, const float* __restrict__ bu1,
    float* __restrict__ ubuf,
    int d1, int d2, int dcv1, int du1)
{
    const int bid = blockIdx.x;
    if (bid < 320) {
        if (d1 < 0) return;
        gates_role<8, HF, WF, 8>(c1_all + (long)d1 * S1SZ, s1_all + (long)d1 * S1SZ,
                                 wg1, bg1, rh1, ug1, bid % 160, bid / 160);
    } else if (bid < 640) {
        if (d2 < 0) return;
        const int bb = bid - 320;
        gates_role<16, HH, WH, 4>(c2_all + (long)d2 * S2SZ, s2_all + (long)d2 * S2SZ,
                                  wg2, bg2, rh2, ug2, bb % 40, bb / 40);
    } else if (bid < 960) {
        if (dcv1 < 0) return;
        conv1p_role(x, w1, b1, c1_all + (long)dcv1 * S1SZ, dcv1, bid - 640);
    } else {
        if (du1 < 0) return;
        up1_role(s2_all + (long)(du1 + 1) * S2SZ, wu1, bu1,
                 s1_all + (long)(du1 + 1) * S1SZ, ubuf, bid - 960);
    }
}

// B(d): cand1(d) [0,160) | conv2(d-1) [160,240) | cand2(d-2) [240,400) |
//       up2(d-3) [400,720)
__global__ __launch_bounds__(256) void k_stepB(
    const float* __restrict__ c1_all, float* __restrict__ s1_all,
    const float* __restrict__ wc1, const float* __restrict__ bc1,
    const float* __restrict__ rh1, const float* __restrict__ ug1,
    const float* __restrict__ w2, const float* __restrict__ b2,
    float* __restrict__ c2_all, float* __restrict__ s2_all,
    const float* __restrict__ wc2, const float* __restrict__ bc2,
    const float* __restrict__ rh2, const float* __restrict__ ug2,
    const float* __restrict__ wu2, const float* __restrict__ bu2,
    const float* __restrict__ ubuf, float* __restrict__ out,
    int d1, int dc, int d2, int du2)
{
    const int bid = blockIdx.x;
    if (bid < 160) {
        if (d1 < 0) return;
        cand_role<8, HF, WF, 8>(c1_all + (long)d1 * S1SZ, rh1, wc1, bc1, ug1,
                                s1_all + (long)d1 * S1SZ, s1_all + (long)(d1 + 1) * S1SZ,
                                bid, 0);
    } else if (bid < 240) {
        if (dc < 0) return;
        const int bb = bid - 160;
        conv2_role(s1_all + (long)(dc + 1) * S1SZ, w2, b2,
                   c2_all + (long)dc * S2SZ, bb % 40, bb / 40);
    } else if (bid < 400) {
        if (d2 < 0) return;
        const int bb = bid - 240;
        cand_role<16, HH, WH, 4>(c2_all + (long)d2 * S2SZ, rh2, wc2, bc2, ug2,
                                 s2_all + (long)d2 * S2SZ, s2_all + (long)(d2 + 1) * S2SZ,
                                 bb % 40, bb / 40);
    } else {
        if (du2 < 0) return;
        up2_role(ubuf, wu2, bu2, out + (long)du2 * (512 * 640), bid - 400);
    }
}

// ---- standalone wrappers (fallback path) ----------------------------------
template<int C, int Ht, int Wt, int CO>
__global__ __launch_bounds__(256) void k_gates(
    const float* __restrict__ a, const float* __restrict__ s,
    const float* __restrict__ w, const float* __restrict__ b,
    float* __restrict__ rh, float* __restrict__ u)
{ gates_role<C, Ht, Wt, CO>(a, s, w, b, rh, u, blockIdx.x, blockIdx.y); }

template<int C, int Ht, int Wt, int CO>
__global__ __launch_bounds__(256) void k_cand(
    const float* __restrict__ a, const float* __restrict__ rh,
    const float* __restrict__ w, const float* __restrict__ b,
    const float* __restrict__ u, const float* __restrict__ sprev,
    float* __restrict__ sout)
{ cand_role<C, Ht, Wt, CO>(a, rh, w, b, u, sprev, sout, blockIdx.x, blockIdx.y); }

__global__ __launch_bounds__(256) void k_conv2w(
    const float* __restrict__ s1, const float* __restrict__ w,
    const float* __restrict__ b, float* __restrict__ c2)
{ conv2_role(s1, w, b, c2, blockIdx.x, blockIdx.y); }

__global__ __launch_bounds__(256) void k_up1(
    const float* __restrict__ s2b, int zs2,
    const float* __restrict__ w, const float* __restrict__ b,
    const float* __restrict__ s1b, int zs1,
    float* __restrict__ ub, int zu)
{
    up1_role(s2b + (long)blockIdx.z * zs2, w, b,
             s1b + (long)blockIdx.z * zs1, ub + (long)blockIdx.z * zu, blockIdx.x);
}

__global__ __launch_bounds__(256) void k_up2(
    const float* __restrict__ ub, int zu,
    const float* __restrict__ w, const float* __restrict__ b,
    float* __restrict__ out, int d0)
{
    up2_role(ub + (long)blockIdx.z * zu, w, b,
             out + (long)(d0 + blockIdx.z) * (512 * 640), blockIdx.x);
}

extern "C" void kernel_launch(void* const* d_in, const int* in_sizes, int n_in,
                              void* d_out, int out_size, void* d_ws, size_t ws_size,
                              hipStream_t stream)
{
    const float* x   = (const float*)d_in[0];
    const float* w1  = (const float*)d_in[1];
    const float* b1  = (const float*)d_in[2];
    const float* wg1 = (const float*)d_in[3];
    const float* bg1 = (const float*)d_in[4];
    const float* wc1 = (const float*)d_in[5];
    const float* bc1 = (const float*)d_in[6];
    const float* w2  = (const float*)d_in[7];
    const float* b2  = (const float*)d_in[8];
    const float* wg2 = (const float*)d_in[9];
    const float* bg2 = (const float*)d_in[10];
    const float* wc2 = (const float*)d_in[11];
    const float* bc2 = (const float*)d_in[12];
    const float* wu1 = (const float*)d_in[13];
    const float* bu1 = (const float*)d_in[14];
    const float* wu2 = (const float*)d_in[15];
    const float* bu2 = (const float*)d_in[16];
    float* out = (float*)d_out;
    float* ws = (float*)d_ws;

    // ---- full-history schedule: skewed fused chains + balanced fold ----
    {
        float* p = ws;
        float* s1_all = p; p += 49L * S1SZ;   // slice 0 = zeros
        float* s2_all = p; p += 49L * S2SZ;
        float* c2_all = p; p += 48L * S2SZ;
        float* rh1 = p; p += S1SZ;
        float* ug1 = p; p += S1SZ;
        float* rh2 = p; p += S2SZ;
        float* ug2 = p; p += S2SZ;
        float* ubuf = p; p += S1SZ;           // single up1->up2 slice (A(d)->B(d))
        float* c1_all = p; p += 48L * S1SZ;
        const size_t need = (size_t)(p - ws) * sizeof(float);
        if (ws_size >= need) {
            hipMemsetAsync(s1_all, 0, (size_t)S1SZ * sizeof(float), stream);
            hipMemsetAsync(s2_all, 0, (size_t)S2SZ * sizeof(float), stream);

            // Prologue: conv1 for slices 0,1 (chain folds in slice d+2).
            k_conv1<<<dim3(80, 1, 2), 256, 0, stream>>>(x, w1, b1, c1_all, 0, S1SZ);
            // Skew (all producers >= 1 dispatch ahead of consumers):
            //   A(d): gates1(d) | gates2(d-2) | conv1(d+2) | up1(d-3)
            //   B(d): cand1(d) | conv2(d-1) | cand2(d-2) | up2(d-3)
            for (int d = 0; d <= 50; ++d) {
                const int g1  = (d < 48) ? d : -1;
                const int g2  = (d >= 2 && d <= 49) ? d - 2 : -1;
                const int cv1 = (d + 2 < 48) ? d + 2 : -1;
                const int u1  = (d >= 3) ? d - 3 : -1;          // <= 47 since d <= 50
                const int cv  = (d >= 1 && d <= 48) ? d - 1 : -1;
                k_stepA<<<dim3(1040), 256, 0, stream>>>(
                    x, w1, b1, c1_all, s1_all, wg1, bg1, rh1, ug1,
                    c2_all, s2_all, wg2, bg2, rh2, ug2,
                    wu1, bu1, ubuf, g1, g2, cv1, u1);
                k_stepB<<<dim3(720), 256, 0, stream>>>(
                    c1_all, s1_all, wc1, bc1, rh1, ug1,
                    w2, b2, c2_all, s2_all, wc2, bc2, rh2, ug2,
                    wu2, bu2, ubuf, out, g1, cv, g2, u1);
            }
            return;
        }
    }

    // ---- fallback: small-workspace interleaved schedule ----
    {
        float* p = ws;
        float* s1 = p; p += S1SZ;
        float* s2 = p; p += S2SZ;
        float* rh1 = p; p += S1SZ;
        float* ug1 = p; p += S1SZ;
        float* c2 = p; p += S2SZ;
        float* rh2 = p; p += S2SZ;
        float* ug2 = p; p += S2SZ;
        float* c1 = p; p += S1SZ;
        float* u = p; p += S1SZ;
        hipMemsetAsync(s1, 0, (size_t)S1SZ * sizeof(float), stream);
        hipMemsetAsync(s2, 0, (size_t)S2SZ * sizeof(float), stream);
        for (int d = 0; d < 48; ++d) {
            k_conv1<<<dim3(80, 1, 1), 256, 0, stream>>>(x, w1, b1, c1, d, 0);
            k_gates<8, HF, WF, 8><<<dim3(160, 2), 256, 0, stream>>>(c1, s1, wg1, bg1, rh1, ug1);
            k_cand <8, HF, WF, 8><<<dim3(160, 1), 256, 0, stream>>>(c1, rh1, wc1, bc1, ug1, s1, s1);
            k_conv2w<<<dim3(40, 2), 256, 0, stream>>>(s1, w2, b2, c2);
            k_gates<16, HH, WH, 8><<<dim3(40, 4), 256, 0, stream>>>(c2, s2, wg2, bg2, rh2, ug2);
            k_cand <16, HH, WH, 8><<<dim3(40, 2), 256, 0, stream>>>(c2, rh2, wc2, bc2, ug2, s2, s2);
            k_up1<<<dim3(80, 1, 1), 256, 0, stream>>>(s2, 0, wu1, bu1, s1, 0, u, 0);
            k_up2<<<dim3(320, 1, 1), 256, 0, stream>>>(u, 0, wu2, bu2, out, d);
        }
    }
}